// Round 2
// baseline (2013.546 us; speedup 1.0000x reference)
//
#include <hip/hip_runtime.h>
#include <cstdint>
#include <cstddef>

#define BB 8
#define NN 16384
#define SS 512
#define KK 32

__device__ __forceinline__ float fm(float a, float b){ return __fmul_rn(a,b); }
__device__ __forceinline__ float fa(float a, float b){ return __fadd_rn(a,b); }
__device__ __forceinline__ float fsb(float a, float b){ return __fsub_rn(a,b); }

// ---------------- per-point squared norm (numpy order: (x^2+y^2)+z^2) ----------------
__global__ void sqnorm_kernel(const float* __restrict__ xyz, float* __restrict__ sqn){
  int gid = blockIdx.x*blockDim.x + threadIdx.x; // B*N
  int b = gid >> 14; int n = gid & (NN-1);
  const float* xb = xyz + (size_t)b*3*NN;
  float x = xb[n], y = xb[NN+n], z = xb[2*NN+n];
  sqn[gid] = fa(fa(fm(x,x),fm(y,y)),fm(z,z));
}

// ---------------- farthest point sampling: 1 block per batch ----------------
// __launch_bounds__(512,2): 8 waves/block, 2 waves/SIMD -> VGPR cap 256.
// Persistent per-thread point arrays need 128 VGPRs; without this the
// compiler capped at 104 VGPRs and spilled (R1: 1240us).
__global__ __launch_bounds__(512, 2) void fps_kernel(const float* __restrict__ xyz,
                                                     float* __restrict__ nxyz,   // ws (B,S,3)
                                                     float* __restrict__ out)    // d_out (B,3,S)
{
  int b = blockIdx.x;
  int t = threadIdx.x;
  const float* xb = xyz + (size_t)b*3*NN;
  float px[32], py[32], pz[32], dist[32];
#pragma unroll
  for (int k=0;k<32;k++){
    int n = k*512 + t;
    px[k]=xb[n]; py[k]=xb[NN+n]; pz[k]=xb[2*NN+n];
    dist[k]=1e10f;
  }
  __shared__ float red[2][8][8]; // [step parity][wave][{v,idx,x,y,z}]
  int wid = t >> 6, lane = t & 63;
  // current centroid coordinates held in registers by every thread
  float cx = xb[0], cy = xb[NN], cz = xb[2*NN];
  for (int step=0; step<SS; ++step){
    if (t==0){
      float* nx = nxyz + ((size_t)b*SS + step)*3;
      nx[0]=cx; nx[1]=cy; nx[2]=cz;
      float* ox = out + (size_t)b*3*SS;
      ox[step]=cx; ox[SS+step]=cy; ox[2*SS+step]=cz;
    }
    float bv = -1.0f; int bi = 0; float bx=0.f, by=0.f, bz=0.f;
#pragma unroll
    for (int k=0;k<32;k++){
      float dx=fsb(px[k],cx), dy=fsb(py[k],cy), dz=fsb(pz[k],cz);
      float d = fa(fa(fm(dx,dx),fm(dy,dy)),fm(dz,dz));
      float dk = fminf(dist[k], d);
      dist[k]=dk;
      // strict > keeps earliest k => smallest index for this thread (idx grows with k)
      if (dk > bv){ bv=dk; bi=k*512+t; bx=px[k]; by=py[k]; bz=pz[k]; }
    }
    // wave(64) butterfly argmax: all lanes converge; carry winner's coords so
    // we never need a dependent global load of the next centroid
#pragma unroll
    for (int off=1; off<64; off<<=1){
      float ov = __shfl_xor(bv, off);
      int   oi = __shfl_xor(bi, off);
      float ocx = __shfl_xor(bx, off);
      float ocy = __shfl_xor(by, off);
      float ocz = __shfl_xor(bz, off);
      bool take = (ov > bv) || (ov == bv && oi < bi);
      if (take){ bv=ov; bi=oi; bx=ocx; by=ocy; bz=ocz; }
    }
    int par = step & 1;
    if (lane==0){
      red[par][wid][0]=bv;
      red[par][wid][1]=__int_as_float(bi);
      red[par][wid][2]=bx;
      red[par][wid][3]=by;
      red[par][wid][4]=bz;
    }
    __syncthreads();
    // every thread redundantly reduces the 8 wave candidates -> same winner,
    // no second barrier (parity double-buffer prevents WAR on red[])
    float v = red[par][0][0]; int i = __float_as_int(red[par][0][1]);
    float x = red[par][0][2], y = red[par][0][3], z = red[par][0][4];
#pragma unroll
    for (int w=1; w<8; w++){
      float wv2 = red[par][w][0]; int wi2 = __float_as_int(red[par][w][1]);
      bool take = (wv2 > v) || (wv2 == v && wi2 < i);
      if (take){ v=wv2; i=wi2; x=red[par][w][2]; y=red[par][w][3]; z=red[par][w][4]; }
    }
    cx=x; cy=y; cz=z;
  }
}

// ---------------- ball query: 1 wave per centroid, early exit at 32 hits ----------------
__global__ void ballq_kernel(const float* __restrict__ xyz,
                             const float* __restrict__ sqn,
                             const float* __restrict__ nxyz,
                             int* __restrict__ gidx)
{
  int wv = (blockIdx.x * (blockDim.x>>6)) + (threadIdx.x>>6); // B*S waves
  int lane = threadIdx.x & 63;
  int b = wv >> 9; int s = wv & (SS-1);
  const float* nx3 = nxyz + ((size_t)b*SS + s)*3;
  float nx=nx3[0], ny=nx3[1], nz=nx3[2];
  float cn = fa(fa(fm(nx,nx),fm(ny,ny)),fm(nz,nz));
  const float* xb = xyz + (size_t)b*3*NN;
  const float* sb = sqn + (size_t)b*NN;
  const float R2 = (float)(0.2*0.2);   // f64 product rounded once to f32
  int* g = gidx + ((size_t)b*SS + s)*KK;
  int cnt = 0; int first_idx = 0;
  for (int base=0; base<NN; base+=64){
    int n = base + lane;
    float x=xb[n], y=xb[NN+n], z=xb[2*NN+n];
    float dot = fa(fa(fm(nx,x),fm(ny,y)),fm(nz,z));
    float sqd = fsb(fa(cn, sb[n]), fm(2.0f, dot));
    bool inb = !(sqd > R2);
    unsigned long long m = __ballot(inb);
    if (m){
      if (cnt==0) first_idx = base + __builtin_ctzll(m);
      int pre = __popcll(m & ((1ull<<lane)-1ull));
      int slot = cnt + pre;
      if (inb && slot < KK) g[slot] = n;
      cnt += __popcll(m);
      if (cnt >= KK) break;
    }
  }
  if (cnt < KK && lane >= cnt && lane < KK) g[lane] = first_idx;
}

// ---------------- layer 0: gather + concat + conv(6->64) ----------------
__global__ __launch_bounds__(256) void mlp0_kernel(const float* __restrict__ xyz,
                            const float* __restrict__ pts,
                            const float* __restrict__ nxyz,
                            const int* __restrict__ gidx,
                            const float* __restrict__ w,    // (64,6)
                            const float* __restrict__ bias,
                            float* __restrict__ y0)         // (B,64,K,S)
{
  int gid = blockIdx.x*blockDim.x + threadIdx.x;  // B*K*S
  int b = gid / (KK*SS);
  int r = gid % (KK*SS);
  int k = r / SS; int s = r % SS;
  int idx = gidx[((size_t)b*SS + s)*KK + k];
  const float* pb = pts + (size_t)b*3*NN;
  const float* xb = xyz + (size_t)b*3*NN;
  const float* nx3 = nxyz + ((size_t)b*SS + s)*3;
  float in[6];
  in[0]=pb[idx]; in[1]=pb[NN+idx]; in[2]=pb[2*NN+idx];
  in[3]=xb[idx]-nx3[0]; in[4]=xb[NN+idx]-nx3[1]; in[5]=xb[2*NN+idx]-nx3[2];
  float* po = y0 + (size_t)b*64*KK*SS + r;
  for (int o=0;o<64;o++){
    float acc = bias[o];
#pragma unroll
    for (int c=0;c<6;c++) acc += in[c]*w[o*6+c];
    po[(size_t)o*KK*SS] = acc;
  }
}

// ---------------- BN stats: one block per channel ----------------
__global__ __launch_bounds__(256) void stats_kernel(const float* __restrict__ y, int C,
                             const float* __restrict__ gamma,
                             const float* __restrict__ beta,
                             float* __restrict__ a, float* __restrict__ c)
{
  int o = blockIdx.x; int t = threadIdx.x;
  double s1=0.0, s2=0.0;
  for (int b=0;b<BB;b++){
    const float* p = y + ((size_t)b*C + o)*KK*SS;
    for (int j=t; j<KK*SS; j+=256){ float v=p[j]; s1 += (double)v; s2 += (double)v*(double)v; }
  }
#pragma unroll
  for (int off=32; off>=1; off>>=1){
    s1 += __shfl_down(s1, off);
    s2 += __shfl_down(s2, off);
  }
  __shared__ double l1[4], l2[4];
  int wid = t>>6;
  if ((t&63)==0){ l1[wid]=s1; l2[wid]=s2; }
  __syncthreads();
  if (t==0){
    double t1=0,t2=0;
    for (int w=0;w<4;w++){ t1+=l1[w]; t2+=l2[w]; }
    double n = (double)BB*KK*SS;
    double m = t1/n;
    double var = t2/n - m*m;
    double inv = 1.0/sqrt(var + 1e-5);
    float sc = (float)((double)gamma[o]*inv);
    a[o]=sc; c[o]=(float)((double)beta[o] - m*(double)sc);
  }
}

// ---------------- conv layer: BN+ReLU applied to input on the fly ----------------
template<int CIN, int COUT>
__global__ __launch_bounds__(256) void mlp_kernel(const float* __restrict__ yin,
                            const float* __restrict__ w,
                            const float* __restrict__ bias,
                            const float* __restrict__ a,
                            const float* __restrict__ cc,
                            float* __restrict__ yout)
{
  int gid = blockIdx.x*blockDim.x + threadIdx.x; // B*K*S
  int b = gid / (KK*SS);
  int r = gid % (KK*SS);
  const float* pin = yin + (size_t)b*CIN*KK*SS + r;
  float x[CIN];
#pragma unroll
  for (int ci=0;ci<CIN;ci++) x[ci] = fmaxf(fmaf(pin[(size_t)ci*KK*SS], a[ci], cc[ci]), 0.0f);
  float* po = yout + (size_t)b*COUT*KK*SS + r;
  for (int o=0;o<COUT;o++){
    float acc = bias[o];
#pragma unroll
    for (int ci=0;ci<CIN;ci++) acc += x[ci]*w[o*CIN+ci];
    po[(size_t)o*KK*SS] = acc;
  }
}

// ---------------- final: BN+ReLU+max over K ----------------
__global__ __launch_bounds__(256) void final_kernel(const float* __restrict__ y2,
                             const float* __restrict__ a,
                             const float* __restrict__ cc,
                             float* __restrict__ out)  // (B,128,S)
{
  int gid = blockIdx.x*blockDim.x + threadIdx.x; // B*128*S
  int b = gid / (128*SS);
  int r = gid % (128*SS);
  int o = r / SS; int s = r % SS;
  const float* p = y2 + ((size_t)b*128 + o)*KK*SS + s;
  float sc=a[o], sh=cc[o];
  float m = 0.0f;  // relu outputs are >= 0, 32 values exist
#pragma unroll
  for (int k=0;k<KK;k++){
    float v = fmaf(p[(size_t)k*SS], sc, sh);
    v = fmaxf(v, 0.0f);
    m = fmaxf(m, v);
  }
  out[gid] = m;
}

extern "C" void kernel_launch(void* const* d_in, const int* in_sizes, int n_in,
                              void* d_out, int out_size, void* d_ws, size_t ws_size,
                              hipStream_t stream)
{
  const float* xyz = (const float*)d_in[0];
  const float* pts = (const float*)d_in[1];
  const float* w0  = (const float*)d_in[2];
  const float* b0  = (const float*)d_in[3];
  const float* g0  = (const float*)d_in[4];
  const float* be0 = (const float*)d_in[5];
  const float* w1  = (const float*)d_in[6];
  const float* b1  = (const float*)d_in[7];
  const float* g1  = (const float*)d_in[8];
  const float* be1 = (const float*)d_in[9];
  const float* w2  = (const float*)d_in[10];
  const float* b2  = (const float*)d_in[11];
  const float* g2  = (const float*)d_in[12];
  const float* be2 = (const float*)d_in[13];
  float* out = (float*)d_out;

  char* ws = (char*)d_ws;
  float* sqn  = (float*)(ws + 0);          // B*N f32          = 524288 B
  float* nxyz = (float*)(ws + 524288);     // B*S*3 f32        = 49152 B
  int*   gidx = (int*)  (ws + 573440);     // B*S*K i32        = 524288 B
  float* st   = (float*)(ws + 1097728);    // 512 f32
  float* a0=st,     *c0=st+64;
  float* a1=st+128, *c1=st+192;
  float* a2=st+256, *c2=st+384;
  // y1 at 4MiB (33.5MB), y2 at 40MiB (67MB), y0 at 76MiB (33.5MB; dead before y2 written)
  float* y1 = (float*)(ws + 4194304);
  float* y2 = (float*)(ws + 41943040);
  float* y0 = (float*)(ws + 79691776);
  (void)ws_size; (void)in_sizes; (void)n_in; (void)out_size;

  sqnorm_kernel<<<dim3(512), dim3(256), 0, stream>>>(xyz, sqn);
  fps_kernel<<<dim3(BB), dim3(512), 0, stream>>>(xyz, nxyz, out);
  ballq_kernel<<<dim3(1024), dim3(256), 0, stream>>>(xyz, sqn, nxyz, gidx);
  mlp0_kernel<<<dim3(512), dim3(256), 0, stream>>>(xyz, pts, nxyz, gidx, w0, b0, y0);
  stats_kernel<<<dim3(64), dim3(256), 0, stream>>>(y0, 64, g0, be0, a0, c0);
  mlp_kernel<64,64><<<dim3(512), dim3(256), 0, stream>>>(y0, w1, b1, a0, c0, y1);
  stats_kernel<<<dim3(64), dim3(256), 0, stream>>>(y1, 64, g1, be1, a1, c1);
  mlp_kernel<64,128><<<dim3(512), dim3(256), 0, stream>>>(y1, w2, b2, a1, c1, y2);
  stats_kernel<<<dim3(128), dim3(256), 0, stream>>>(y2, 128, g2, be2, a2, c2);
  final_kernel<<<dim3(2048), dim3(256), 0, stream>>>(y2, a2, c2, out + BB*3*SS);
}

// Round 3
// 1688.598 us; speedup vs baseline: 1.1924x; 1.1924x over previous
//
#include <hip/hip_runtime.h>
#include <cstdint>
#include <cstddef>

#define BB 8
#define NN 16384
#define SS 512
#define KK 32

__device__ __forceinline__ float fm(float a, float b){ return __fmul_rn(a,b); }
__device__ __forceinline__ float fa(float a, float b){ return __fadd_rn(a,b); }
__device__ __forceinline__ float fsb(float a, float b){ return __fsub_rn(a,b); }

// ---------------- per-point squared norm (numpy order: (x^2+y^2)+z^2) ----------------
__global__ void sqnorm_kernel(const float* __restrict__ xyz, float* __restrict__ sqn){
  int gid = blockIdx.x*blockDim.x + threadIdx.x; // B*N
  int b = gid >> 14; int n = gid & (NN-1);
  const float* xb = xyz + (size_t)b*3*NN;
  float x = xb[n], y = xb[NN+n], z = xb[2*NN+n];
  sqn[gid] = fa(fa(fm(x,x),fm(y,y)),fm(z,z));
}

// ---------------- farthest point sampling: 1 block (1024 thr) per batch ----------------
// 16 pts/thread -> 64 data VGPRs; __launch_bounds__(1024,4) caps VGPR at 128 so
// everything stays in arch VGPRs (R2: 32 pts/thread forced arrays into AGPRs,
// +5 accvgpr insts/iter at only 2 waves/SIMD).
// Argmax is carried as a packed u64 key = (dist_bits<<32)|(16384-idx): dist>=0 so
// float bits are monotone as uint; tie resolves to smaller idx (numpy argmax).
// One barrier/step: leaders write keys to parity-buffered LDS; every lane then
// reads redk[lane&15] (4-way broadcast) and runs a 4-stage intra-16 butterfly so
// all 64 lanes converge -- no second barrier, no serial thread-0 phase. Next
// centroid coords via same-address broadcast global load (L1/L2 resident).
__global__ __launch_bounds__(1024, 4) void fps_kernel(const float* __restrict__ xyz,
                                                      float* __restrict__ nxyz,   // ws (B,S,3)
                                                      float* __restrict__ out)    // d_out (B,3,S)
{
  int b = blockIdx.x;
  int t = threadIdx.x;           // 0..1023
  const float* xb = xyz + (size_t)b*3*NN;
  float px[16], py[16], pz[16], dist[16];
#pragma unroll
  for (int k=0;k<16;k++){
    int n = k*1024 + t;
    px[k]=xb[n]; py[k]=xb[NN+n]; pz[k]=xb[2*NN+n];
    dist[k]=1e10f;
  }
  __shared__ unsigned long long redk[2][16];
  int wid = t >> 6, lane = t & 63;
  float cx = xb[0], cy = xb[NN], cz = xb[2*NN];
  for (int step=0; step<SS; ++step){
    if (t==0){
      float* nx = nxyz + ((size_t)b*SS + step)*3;
      nx[0]=cx; nx[1]=cy; nx[2]=cz;
      float* ox = out + (size_t)b*3*SS;
      ox[step]=cx; ox[SS+step]=cy; ox[2*SS+step]=cz;
    }
    float bv = -1.0f; int bk = 0;
#pragma unroll
    for (int k=0;k<16;k++){
      float dx=fsb(px[k],cx), dy=fsb(py[k],cy), dz=fsb(pz[k],cz);
      float d = fa(fa(fm(dx,dx),fm(dy,dy)),fm(dz,dz));
      float dk = fminf(dist[k], d);
      dist[k]=dk;
      // strict > keeps earliest k => smallest index for this thread
      if (dk > bv){ bv=dk; bk=k; }
    }
    int bi = (bk<<10) | t;
    unsigned long long key = ((unsigned long long)__float_as_uint(bv) << 32)
                           | (unsigned)(16384 - bi);
    // wave(64) butterfly max on packed key
#pragma unroll
    for (int off=1; off<64; off<<=1){
      unsigned long long ok = __shfl_xor(key, off);
      if (ok > key) key = ok;
    }
    int par = step & 1;
    if (lane==0) redk[par][wid] = key;
    __syncthreads();
    // every lane reads one of the 16 candidates (4-way same-address broadcast),
    // then 4-stage butterfly within each group of 16 -> all 64 lanes converge
    unsigned long long k2 = redk[par][lane & 15];
#pragma unroll
    for (int off=1; off<16; off<<=1){
      unsigned long long ok = __shfl_xor(k2, off);
      if (ok > k2) k2 = ok;
    }
    int i = 16384 - (int)(unsigned)(k2 & 0xFFFFFFFFull);
    cx = xb[i]; cy = xb[NN+i]; cz = xb[2*NN+i];
  }
}

// ---------------- ball query: 1 wave per centroid, early exit at 32 hits ----------------
__global__ void ballq_kernel(const float* __restrict__ xyz,
                             const float* __restrict__ sqn,
                             const float* __restrict__ nxyz,
                             int* __restrict__ gidx)
{
  int wv = (blockIdx.x * (blockDim.x>>6)) + (threadIdx.x>>6); // B*S waves
  int lane = threadIdx.x & 63;
  int b = wv >> 9; int s = wv & (SS-1);
  const float* nx3 = nxyz + ((size_t)b*SS + s)*3;
  float nx=nx3[0], ny=nx3[1], nz=nx3[2];
  float cn = fa(fa(fm(nx,nx),fm(ny,ny)),fm(nz,nz));
  const float* xb = xyz + (size_t)b*3*NN;
  const float* sb = sqn + (size_t)b*NN;
  const float R2 = (float)(0.2*0.2);   // f64 product rounded once to f32
  int* g = gidx + ((size_t)b*SS + s)*KK;
  int cnt = 0; int first_idx = 0;
  for (int base=0; base<NN; base+=64){
    int n = base + lane;
    float x=xb[n], y=xb[NN+n], z=xb[2*NN+n];
    float dot = fa(fa(fm(nx,x),fm(ny,y)),fm(nz,z));
    float sqd = fsb(fa(cn, sb[n]), fm(2.0f, dot));
    bool inb = !(sqd > R2);
    unsigned long long m = __ballot(inb);
    if (m){
      if (cnt==0) first_idx = base + __builtin_ctzll(m);
      int pre = __popcll(m & ((1ull<<lane)-1ull));
      int slot = cnt + pre;
      if (inb && slot < KK) g[slot] = n;
      cnt += __popcll(m);
      if (cnt >= KK) break;
    }
  }
  if (cnt < KK && lane >= cnt && lane < KK) g[lane] = first_idx;
}

// ---------------- layer 0: gather + concat + conv(6->64) ----------------
__global__ __launch_bounds__(256) void mlp0_kernel(const float* __restrict__ xyz,
                            const float* __restrict__ pts,
                            const float* __restrict__ nxyz,
                            const int* __restrict__ gidx,
                            const float* __restrict__ w,    // (64,6)
                            const float* __restrict__ bias,
                            float* __restrict__ y0)         // (B,64,K,S)
{
  int gid = blockIdx.x*blockDim.x + threadIdx.x;  // B*K*S
  int b = gid / (KK*SS);
  int r = gid % (KK*SS);
  int k = r / SS; int s = r % SS;
  int idx = gidx[((size_t)b*SS + s)*KK + k];
  const float* pb = pts + (size_t)b*3*NN;
  const float* xb = xyz + (size_t)b*3*NN;
  const float* nx3 = nxyz + ((size_t)b*SS + s)*3;
  float in[6];
  in[0]=pb[idx]; in[1]=pb[NN+idx]; in[2]=pb[2*NN+idx];
  in[3]=xb[idx]-nx3[0]; in[4]=xb[NN+idx]-nx3[1]; in[5]=xb[2*NN+idx]-nx3[2];
  float* po = y0 + (size_t)b*64*KK*SS + r;
  for (int o=0;o<64;o++){
    float acc = bias[o];
#pragma unroll
    for (int c=0;c<6;c++) acc += in[c]*w[o*6+c];
    po[(size_t)o*KK*SS] = acc;
  }
}

// ---------------- BN stats: one block per channel ----------------
__global__ __launch_bounds__(256) void stats_kernel(const float* __restrict__ y, int C,
                             const float* __restrict__ gamma,
                             const float* __restrict__ beta,
                             float* __restrict__ a, float* __restrict__ c)
{
  int o = blockIdx.x; int t = threadIdx.x;
  double s1=0.0, s2=0.0;
  for (int b=0;b<BB;b++){
    const float* p = y + ((size_t)b*C + o)*KK*SS;
    for (int j=t; j<KK*SS; j+=256){ float v=p[j]; s1 += (double)v; s2 += (double)v*(double)v; }
  }
#pragma unroll
  for (int off=32; off>=1; off>>=1){
    s1 += __shfl_down(s1, off);
    s2 += __shfl_down(s2, off);
  }
  __shared__ double l1[4], l2[4];
  int wid = t>>6;
  if ((t&63)==0){ l1[wid]=s1; l2[wid]=s2; }
  __syncthreads();
  if (t==0){
    double t1=0,t2=0;
    for (int w=0;w<4;w++){ t1+=l1[w]; t2+=l2[w]; }
    double n = (double)BB*KK*SS;
    double m = t1/n;
    double var = t2/n - m*m;
    double inv = 1.0/sqrt(var + 1e-5);
    float sc = (float)((double)gamma[o]*inv);
    a[o]=sc; c[o]=(float)((double)beta[o] - m*(double)sc);
  }
}

// ---------------- conv layer: BN+ReLU applied to input on the fly ----------------
template<int CIN, int COUT>
__global__ __launch_bounds__(256) void mlp_kernel(const float* __restrict__ yin,
                            const float* __restrict__ w,
                            const float* __restrict__ bias,
                            const float* __restrict__ a,
                            const float* __restrict__ cc,
                            float* __restrict__ yout)
{
  int gid = blockIdx.x*blockDim.x + threadIdx.x; // B*K*S
  int b = gid / (KK*SS);
  int r = gid % (KK*SS);
  const float* pin = yin + (size_t)b*CIN*KK*SS + r;
  float x[CIN];
#pragma unroll
  for (int ci=0;ci<CIN;ci++) x[ci] = fmaxf(fmaf(pin[(size_t)ci*KK*SS], a[ci], cc[ci]), 0.0f);
  float* po = yout + (size_t)b*COUT*KK*SS + r;
  for (int o=0;o<COUT;o++){
    float acc = bias[o];
#pragma unroll
    for (int ci=0;ci<CIN;ci++) acc += x[ci]*w[o*CIN+ci];
    po[(size_t)o*KK*SS] = acc;
  }
}

// ---------------- final: BN+ReLU+max over K ----------------
__global__ __launch_bounds__(256) void final_kernel(const float* __restrict__ y2,
                             const float* __restrict__ a,
                             const float* __restrict__ cc,
                             float* __restrict__ out)  // (B,128,S)
{
  int gid = blockIdx.x*blockDim.x + threadIdx.x; // B*128*S
  int b = gid / (128*SS);
  int r = gid % (128*SS);
  int o = r / SS; int s = r % SS;
  const float* p = y2 + ((size_t)b*128 + o)*KK*SS + s;
  float sc=a[o], sh=cc[o];
  float m = 0.0f;  // relu outputs are >= 0, 32 values exist
#pragma unroll
  for (int k=0;k<KK;k++){
    float v = fmaf(p[(size_t)k*SS], sc, sh);
    v = fmaxf(v, 0.0f);
    m = fmaxf(m, v);
  }
  out[gid] = m;
}

extern "C" void kernel_launch(void* const* d_in, const int* in_sizes, int n_in,
                              void* d_out, int out_size, void* d_ws, size_t ws_size,
                              hipStream_t stream)
{
  const float* xyz = (const float*)d_in[0];
  const float* pts = (const float*)d_in[1];
  const float* w0  = (const float*)d_in[2];
  const float* b0  = (const float*)d_in[3];
  const float* g0  = (const float*)d_in[4];
  const float* be0 = (const float*)d_in[5];
  const float* w1  = (const float*)d_in[6];
  const float* b1  = (const float*)d_in[7];
  const float* g1  = (const float*)d_in[8];
  const float* be1 = (const float*)d_in[9];
  const float* w2  = (const float*)d_in[10];
  const float* b2  = (const float*)d_in[11];
  const float* g2  = (const float*)d_in[12];
  const float* be2 = (const float*)d_in[13];
  float* out = (float*)d_out;

  char* ws = (char*)d_ws;
  float* sqn  = (float*)(ws + 0);          // B*N f32          = 524288 B
  float* nxyz = (float*)(ws + 524288);     // B*S*3 f32        = 49152 B
  int*   gidx = (int*)  (ws + 573440);     // B*S*K i32        = 524288 B
  float* st   = (float*)(ws + 1097728);    // 512 f32
  float* a0=st,     *c0=st+64;
  float* a1=st+128, *c1=st+192;
  float* a2=st+256, *c2=st+384;
  // y1 at 4MiB (33.5MB), y2 at 40MiB (67MB), y0 at 76MiB (33.5MB; dead before y2 written)
  float* y1 = (float*)(ws + 4194304);
  float* y2 = (float*)(ws + 41943040);
  float* y0 = (float*)(ws + 79691776);
  (void)ws_size; (void)in_sizes; (void)n_in; (void)out_size;

  sqnorm_kernel<<<dim3(512), dim3(256), 0, stream>>>(xyz, sqn);
  fps_kernel<<<dim3(BB), dim3(1024), 0, stream>>>(xyz, nxyz, out);
  ballq_kernel<<<dim3(1024), dim3(256), 0, stream>>>(xyz, sqn, nxyz, gidx);
  mlp0_kernel<<<dim3(512), dim3(256), 0, stream>>>(xyz, pts, nxyz, gidx, w0, b0, y0);
  stats_kernel<<<dim3(64), dim3(256), 0, stream>>>(y0, 64, g0, be0, a0, c0);
  mlp_kernel<64,64><<<dim3(512), dim3(256), 0, stream>>>(y0, w1, b1, a0, c0, y1);
  stats_kernel<<<dim3(64), dim3(256), 0, stream>>>(y1, 64, g1, be1, a1, c1);
  mlp_kernel<64,128><<<dim3(512), dim3(256), 0, stream>>>(y1, w2, b2, a1, c1, y2);
  stats_kernel<<<dim3(128), dim3(256), 0, stream>>>(y2, 128, g2, be2, a2, c2);
  final_kernel<<<dim3(2048), dim3(256), 0, stream>>>(y2, a2, c2, out + BB*3*SS);
}

// Round 5
// 1307.967 us; speedup vs baseline: 1.5394x; 1.2910x over previous
//
#include <hip/hip_runtime.h>
#include <cstdint>
#include <cstddef>

#define BB 8
#define NN 16384
#define SS 512
#define KK 32

__device__ __forceinline__ float fm(float a, float b){ return __fmul_rn(a,b); }
__device__ __forceinline__ float fa(float a, float b){ return __fadd_rn(a,b); }
__device__ __forceinline__ float fsb(float a, float b){ return __fsub_rn(a,b); }

// ---------------- per-point squared norm (numpy order: (x^2+y^2)+z^2) ----------------
__global__ void sqnorm_kernel(const float* __restrict__ xyz, float* __restrict__ sqn){
  int gid = blockIdx.x*blockDim.x + threadIdx.x; // B*N
  int b = gid >> 14; int n = gid & (NN-1);
  const float* xb = xyz + (size_t)b*3*NN;
  float x = xb[n], y = xb[NN+n], z = xb[2*NN+n];
  sqn[gid] = fa(fa(fm(x,x),fm(y,y)),fm(z,z));
}

// ---------------- farthest point sampling: 1 block (1024 thr) per batch ----------------
// VERBATIM R3 kernel (passed validation + post-timing at 960us). R4's
// __launch_bounds__(512,1) variant broke post-timing revalidation (output 0
// diverged after graph replay): min-waves=1 with an 8-wave block is an
// unsatisfiable occupancy contract. DO NOT change launch config here without
// re-verifying post-timing.
__global__ __launch_bounds__(1024, 4) void fps_kernel(const float* __restrict__ xyz,
                                                      float* __restrict__ nxyz,   // ws (B,S,3)
                                                      float* __restrict__ out)    // d_out (B,3,S)
{
  int b = blockIdx.x;
  int t = threadIdx.x;           // 0..1023
  const float* xb = xyz + (size_t)b*3*NN;
  float px[16], py[16], pz[16], dist[16];
#pragma unroll
  for (int k=0;k<16;k++){
    int n = k*1024 + t;
    px[k]=xb[n]; py[k]=xb[NN+n]; pz[k]=xb[2*NN+n];
    dist[k]=1e10f;
  }
  __shared__ unsigned long long redk[2][16];
  int wid = t >> 6, lane = t & 63;
  float cx = xb[0], cy = xb[NN], cz = xb[2*NN];
  for (int step=0; step<SS; ++step){
    if (t==0){
      float* nx = nxyz + ((size_t)b*SS + step)*3;
      nx[0]=cx; nx[1]=cy; nx[2]=cz;
      float* ox = out + (size_t)b*3*SS;
      ox[step]=cx; ox[SS+step]=cy; ox[2*SS+step]=cz;
    }
    float bv = -1.0f; int bk = 0;
#pragma unroll
    for (int k=0;k<16;k++){
      float dx=fsb(px[k],cx), dy=fsb(py[k],cy), dz=fsb(pz[k],cz);
      float d = fa(fa(fm(dx,dx),fm(dy,dy)),fm(dz,dz));
      float dk = fminf(dist[k], d);
      dist[k]=dk;
      // strict > keeps earliest k => smallest index for this thread
      if (dk > bv){ bv=dk; bk=k; }
    }
    int bi = (bk<<10) | t;
    unsigned long long key = ((unsigned long long)__float_as_uint(bv) << 32)
                           | (unsigned)(16384 - bi);
    // wave(64) butterfly max on packed key
#pragma unroll
    for (int off=1; off<64; off<<=1){
      unsigned long long ok = __shfl_xor(key, off);
      if (ok > key) key = ok;
    }
    int par = step & 1;
    if (lane==0) redk[par][wid] = key;
    __syncthreads();
    // every lane reads one of the 16 candidates (4-way same-address broadcast),
    // then 4-stage butterfly within each group of 16 -> all 64 lanes converge
    unsigned long long k2 = redk[par][lane & 15];
#pragma unroll
    for (int off=1; off<16; off<<=1){
      unsigned long long ok = __shfl_xor(k2, off);
      if (ok > k2) k2 = ok;
    }
    int i = 16384 - (int)(unsigned)(k2 & 0xFFFFFFFFull);
    cx = xb[i]; cy = xb[NN+i]; cz = xb[2*NN+i];
  }
}

// ---------------- ball query: 1 wave per centroid, early exit at 32 hits ----------------
__global__ void ballq_kernel(const float* __restrict__ xyz,
                             const float* __restrict__ sqn,
                             const float* __restrict__ nxyz,
                             int* __restrict__ gidx)
{
  int wv = (blockIdx.x * (blockDim.x>>6)) + (threadIdx.x>>6); // B*S waves
  int lane = threadIdx.x & 63;
  int b = wv >> 9; int s = wv & (SS-1);
  const float* nx3 = nxyz + ((size_t)b*SS + s)*3;
  float nx=nx3[0], ny=nx3[1], nz=nx3[2];
  float cn = fa(fa(fm(nx,nx),fm(ny,ny)),fm(nz,nz));
  const float* xb = xyz + (size_t)b*3*NN;
  const float* sb = sqn + (size_t)b*NN;
  const float R2 = (float)(0.2*0.2);   // f64 product rounded once to f32
  int* g = gidx + ((size_t)b*SS + s)*KK;
  int cnt = 0; int first_idx = 0;
  for (int base=0; base<NN; base+=64){
    int n = base + lane;
    float x=xb[n], y=xb[NN+n], z=xb[2*NN+n];
    float dot = fa(fa(fm(nx,x),fm(ny,y)),fm(nz,z));
    float sqd = fsb(fa(cn, sb[n]), fm(2.0f, dot));
    bool inb = !(sqd > R2);
    unsigned long long m = __ballot(inb);
    if (m){
      if (cnt==0) first_idx = base + __builtin_ctzll(m);
      int pre = __popcll(m & ((1ull<<lane)-1ull));
      int slot = cnt + pre;
      if (inb && slot < KK) g[slot] = n;
      cnt += __popcll(m);
      if (cnt >= KK) break;
    }
  }
  if (cnt < KK && lane >= cnt && lane < KK) g[lane] = first_idx;
}

// ---------------- layer 0: gather + concat + conv(6->64) ----------------
__global__ __launch_bounds__(256) void mlp0_kernel(const float* __restrict__ xyz,
                            const float* __restrict__ pts,
                            const float* __restrict__ nxyz,
                            const int* __restrict__ gidx,
                            const float* __restrict__ w,    // (64,6)
                            const float* __restrict__ bias,
                            float* __restrict__ y0)         // (B,64,K,S)
{
  int gid = blockIdx.x*blockDim.x + threadIdx.x;  // B*K*S
  int b = gid / (KK*SS);
  int r = gid % (KK*SS);
  int k = r / SS; int s = r % SS;
  int idx = gidx[((size_t)b*SS + s)*KK + k];
  const float* pb = pts + (size_t)b*3*NN;
  const float* xb = xyz + (size_t)b*3*NN;
  const float* nx3 = nxyz + ((size_t)b*SS + s)*3;
  float in[6];
  in[0]=pb[idx]; in[1]=pb[NN+idx]; in[2]=pb[2*NN+idx];
  in[3]=xb[idx]-nx3[0]; in[4]=xb[NN+idx]-nx3[1]; in[5]=xb[2*NN+idx]-nx3[2];
  float* po = y0 + (size_t)b*64*KK*SS + r;
  for (int o=0;o<64;o++){
    float acc = bias[o];
#pragma unroll
    for (int c=0;c<6;c++) acc += in[c]*w[o*6+c];
    po[(size_t)o*KK*SS] = acc;
  }
}

// ---------------- BN stats, pass 1: per-(channel,batch) partial sums ----------------
// grid = C*8 blocks; block (o, b) reads the contiguous 64KB run y[b][o][:][:]
// with float4 loads; deterministic partial (s1,s2) per block -> psum (no atomics).
__global__ __launch_bounds__(256) void stats_part_kernel(const float* __restrict__ y, int C,
                                                         double* __restrict__ psum)
{
  int o = blockIdx.x >> 3; int b = blockIdx.x & 7;
  int t = threadIdx.x;
  const float4* p = (const float4*)(y + ((size_t)b*C + o)*KK*SS);
  double s1=0.0, s2=0.0;
#pragma unroll
  for (int i=0;i<16;i++){
    float4 v = p[t + i*256];
    double x0=v.x, x1=v.y, x2=v.z, x3=v.w;
    s1 += x0+x1; s1 += x2+x3;
    s2 += x0*x0 + x1*x1;
    s2 += x2*x2 + x3*x3;
  }
#pragma unroll
  for (int off=32; off>=1; off>>=1){
    s1 += __shfl_down(s1, off);
    s2 += __shfl_down(s2, off);
  }
  __shared__ double l1[4], l2[4];
  int wid = t>>6;
  if ((t&63)==0){ l1[wid]=s1; l2[wid]=s2; }
  __syncthreads();
  if (t==0){
    double t1=l1[0]+l1[1]+l1[2]+l1[3];
    double t2=l2[0]+l2[1]+l2[2]+l2[3];
    psum[(o*8+b)*2+0]=t1;
    psum[(o*8+b)*2+1]=t2;
  }
}

// ---------------- BN stats, pass 2: finalize scale/shift ----------------
__global__ void stats_fin_kernel(const double* __restrict__ psum, int C,
                                 const float* __restrict__ gamma,
                                 const float* __restrict__ beta,
                                 float* __restrict__ a, float* __restrict__ c)
{
  int o = threadIdx.x;
  if (o >= C) return;
  double t1=0.0, t2=0.0;
#pragma unroll
  for (int b=0;b<8;b++){ t1 += psum[(o*8+b)*2+0]; t2 += psum[(o*8+b)*2+1]; }
  double n = (double)BB*KK*SS;
  double m = t1/n;
  double var = t2/n - m*m;
  double inv = 1.0/sqrt(var + 1e-5);
  float sc = (float)((double)gamma[o]*inv);
  a[o]=sc; c[o]=(float)((double)beta[o] - m*(double)sc);
}

// ---------------- conv layer: BN+ReLU applied to input on the fly ----------------
template<int CIN, int COUT>
__global__ __launch_bounds__(256) void mlp_kernel(const float* __restrict__ yin,
                            const float* __restrict__ w,
                            const float* __restrict__ bias,
                            const float* __restrict__ a,
                            const float* __restrict__ cc,
                            float* __restrict__ yout)
{
  int gid = blockIdx.x*blockDim.x + threadIdx.x; // B*K*S
  int b = gid / (KK*SS);
  int r = gid % (KK*SS);
  const float* pin = yin + (size_t)b*CIN*KK*SS + r;
  float x[CIN];
#pragma unroll
  for (int ci=0;ci<CIN;ci++) x[ci] = fmaxf(fmaf(pin[(size_t)ci*KK*SS], a[ci], cc[ci]), 0.0f);
  float* po = yout + (size_t)b*COUT*KK*SS + r;
  for (int o=0;o<COUT;o++){
    float acc = bias[o];
#pragma unroll
    for (int ci=0;ci<CIN;ci++) acc += x[ci]*w[o*CIN+ci];
    po[(size_t)o*KK*SS] = acc;
  }
}

// ---------------- final: BN+ReLU+max over K, float4 ----------------
__global__ __launch_bounds__(256) void final_kernel(const float* __restrict__ y2,
                             const float* __restrict__ a,
                             const float* __restrict__ cc,
                             float* __restrict__ out)  // (B,128,S)
{
  int gid = blockIdx.x*blockDim.x + threadIdx.x; // B*128*(S/4)
  int b = gid / (128*128);
  int r = gid % (128*128);
  int o = r >> 7; int s4 = (r & 127);
  const float4* p = (const float4*)(y2 + ((size_t)b*128 + o)*KK*SS) + s4;
  float sc=a[o], sh=cc[o];
  float m0=0.f,m1=0.f,m2=0.f,m3=0.f;  // relu outputs >= 0, 32 values exist
#pragma unroll
  for (int k=0;k<KK;k++){
    float4 v = p[k*(SS/4)];
    m0 = fmaxf(m0, fmaxf(fmaf(v.x, sc, sh), 0.0f));
    m1 = fmaxf(m1, fmaxf(fmaf(v.y, sc, sh), 0.0f));
    m2 = fmaxf(m2, fmaxf(fmaf(v.z, sc, sh), 0.0f));
    m3 = fmaxf(m3, fmaxf(fmaf(v.w, sc, sh), 0.0f));
  }
  float4* po = (float4*)(out + ((size_t)b*128 + o)*SS) + s4;
  *po = make_float4(m0,m1,m2,m3);
}

extern "C" void kernel_launch(void* const* d_in, const int* in_sizes, int n_in,
                              void* d_out, int out_size, void* d_ws, size_t ws_size,
                              hipStream_t stream)
{
  const float* xyz = (const float*)d_in[0];
  const float* pts = (const float*)d_in[1];
  const float* w0  = (const float*)d_in[2];
  const float* b0  = (const float*)d_in[3];
  const float* g0  = (const float*)d_in[4];
  const float* be0 = (const float*)d_in[5];
  const float* w1  = (const float*)d_in[6];
  const float* b1  = (const float*)d_in[7];
  const float* g1  = (const float*)d_in[8];
  const float* be1 = (const float*)d_in[9];
  const float* w2  = (const float*)d_in[10];
  const float* b2  = (const float*)d_in[11];
  const float* g2  = (const float*)d_in[12];
  const float* be2 = (const float*)d_in[13];
  float* out = (float*)d_out;

  char* ws = (char*)d_ws;
  float*  sqn  = (float*) (ws + 0);          // B*N f32          = 524288 B
  float*  nxyz = (float*) (ws + 524288);     // B*S*3 f32        = 49152 B
  int*    gidx = (int*)   (ws + 573440);     // B*S*K i32        = 524288 B
  float*  st   = (float*) (ws + 1097728);    // 512 f32 (a/c per layer)
  double* ps0  = (double*)(ws + 1099776);    // 64*8*2 f64  = 8192 B
  double* ps1  = (double*)(ws + 1107968);    // 64*8*2 f64  = 8192 B
  double* ps2  = (double*)(ws + 1116160);    // 128*8*2 f64 = 16384 B
  float* a0=st,     *c0=st+64;
  float* a1=st+128, *c1=st+192;
  float* a2=st+256, *c2=st+384;
  // y1 at 4MiB (33.5MB), y2 at 40MiB (67MB), y0 at 76MiB (33.5MB; dead before y2 written)
  float* y1 = (float*)(ws + 4194304);
  float* y2 = (float*)(ws + 41943040);
  float* y0 = (float*)(ws + 79691776);
  (void)ws_size; (void)in_sizes; (void)n_in; (void)out_size;

  sqnorm_kernel<<<dim3(512), dim3(256), 0, stream>>>(xyz, sqn);
  fps_kernel<<<dim3(BB), dim3(1024), 0, stream>>>(xyz, nxyz, out);
  ballq_kernel<<<dim3(1024), dim3(256), 0, stream>>>(xyz, sqn, nxyz, gidx);
  mlp0_kernel<<<dim3(512), dim3(256), 0, stream>>>(xyz, pts, nxyz, gidx, w0, b0, y0);
  stats_part_kernel<<<dim3(64*8), dim3(256), 0, stream>>>(y0, 64, ps0);
  stats_fin_kernel<<<dim3(1), dim3(64), 0, stream>>>(ps0, 64, g0, be0, a0, c0);
  mlp_kernel<64,64><<<dim3(512), dim3(256), 0, stream>>>(y0, w1, b1, a0, c0, y1);
  stats_part_kernel<<<dim3(64*8), dim3(256), 0, stream>>>(y1, 64, ps1);
  stats_fin_kernel<<<dim3(1), dim3(64), 0, stream>>>(ps1, 64, g1, be1, a1, c1);
  mlp_kernel<64,128><<<dim3(512), dim3(256), 0, stream>>>(y1, w2, b2, a1, c1, y2);
  stats_part_kernel<<<dim3(128*8), dim3(256), 0, stream>>>(y2, 128, ps2);
  stats_fin_kernel<<<dim3(1), dim3(128), 0, stream>>>(ps2, 128, g2, be2, a2, c2);
  final_kernel<<<dim3(512), dim3(256), 0, stream>>>(y2, a2, c2, out + BB*3*SS);
}